// Round 3
// baseline (359.466 us; speedup 1.0000x reference)
//
#include <hip/hip_runtime.h>
#include <hip/hip_bf16.h>
#include <math.h>

// B=8, H=W=128, C=hidden=256, N=16384, Mtot=131072.
#define Hc   128
#define Wc   128
#define Cc   256
#define Nc   (Hc * Wc)
#define Bn   8
#define Mtot (Bn * Nc)          // 131072
#define CSZ  52                 // ceil(256/5)
#define SPAD 2

typedef unsigned short ushort4v __attribute__((ext_vector_type(4)));
typedef unsigned short ushort8  __attribute__((ext_vector_type(8)));
typedef __bf16         bf16x8   __attribute__((ext_vector_type(8)));
typedef float          f32x4    __attribute__((ext_vector_type(4)));

__device__ __forceinline__ float bf2f(unsigned short u) {
    return __uint_as_float(((unsigned)u) << 16);
}
__device__ __forceinline__ unsigned short f2bf(float f) {   // RNE
    unsigned u = __float_as_uint(f);
    return (unsigned short)((u + 0x7fffu + ((u >> 16) & 1u)) >> 16);
}
// pack two floats -> two bf16 (a -> low16). Round-half-up (ok vs bf16 eps).
__device__ __forceinline__ unsigned pk2bf(float a, float b) {
    unsigned ua = __float_as_uint(a) + 0x8000u;
    unsigned ub = __float_as_uint(b) + 0x8000u;
    return __builtin_amdgcn_perm(ub, ua, 0x07060302);
}
__device__ __forceinline__ void async16(const void* g, void* l) {
    __builtin_amdgcn_global_load_lds(
        (const __attribute__((address_space(1))) unsigned*)g,
        (__attribute__((address_space(3))) unsigned*)l, 16, 0, 0);
}

// Counted-vmcnt fence + raw barrier (T4): never drain vmcnt to 0 mid-loop.
// lgkmcnt(0) makes this wave's ds_writes visible before the barrier.
#define FENCE(vm) asm volatile("s_waitcnt vmcnt(" #vm ") lgkmcnt(0)\n\ts_barrier" ::: "memory")

// ---------------------------------------------------------------------------
// P0: w1 fp32 -> bf16 (into d_out head, dead until fc2 rewrites all of out);
//     dw_w [ch][tap] -> dwT [tap][ch] fp32.
// ---------------------------------------------------------------------------
__global__ __launch_bounds__(256)
void wprep_kernel(const float* __restrict__ w1, const float* __restrict__ dw_w,
                  unsigned short* __restrict__ w1b, float* __restrict__ dwT)
{
    const int g = blockIdx.x * 256 + threadIdx.x;   // 16384 threads
    {
        float4 a = *(const float4*)(w1 + (size_t)g * 4);
        ushort4v o = { f2bf(a.x), f2bf(a.y), f2bf(a.z), f2bf(a.w) };
        *(ushort4v*)(w1b + (size_t)g * 4) = o;
    }
    if (g < 9 * Cc) dwT[(g % 9) * Cc + g / 9] = dw_w[g];
}

// ---------------------------------------------------------------------------
// K1: h1 = shiftH(x) @ w1^T + b1. 128x128 tile, BK=32, 16x16x32 MFMA.
// Deep pipeline: B via async16 3-buffer issued 2 steps ahead; A fp32 loads
// 2 steps ahead into ping-pong regs, packed+ds_written 1 step ahead.
// One raw barrier per step with counted vmcnt(6) — loads stay in flight
// across barriers (T4). All LDS panels XOR slot-swizzled (async16 side via
// source-address XOR, LDS linear; reg side via write-address XOR); read XOR
// folds into lane constant kqx. 16-lane ds_read groups: 8-way -> 2-way.
// LDS 40960 B (As 2x8K + Bs 3x8K; Cs epilogue unions) -> 4 blocks/CU.
// ---------------------------------------------------------------------------
__global__ __launch_bounds__(256)
void fc1_mfma_kernel(const float* __restrict__ x, const unsigned short* __restrict__ w1b,
                     const float* __restrict__ b1, unsigned short* __restrict__ h1)
{
    __shared__ __align__(16) unsigned char smem[40960];
    __bf16* As = (__bf16*)smem;                     // [2][128][32] XOR-written
    __bf16* Bs = (__bf16*)(smem + 16384);           // [3][128][32] XOR via src
    unsigned short* Cs = (unsigned short*)smem;     // [128][136] epilogue

    const int tid  = threadIdx.x;
    const int lane = tid & 63;
    const int wave = tid >> 6;
    const int wm = (wave >> 1) * 64, wn = (wave & 1) * 64;

    // nwg = 2048 (div by 8): bijective XCD swizzle; column-tile pair adjacent.
    const int lid = ((blockIdx.x & 7) << 8) | (blockIdx.x >> 3);
    const int bx  = lid >> 1;                  // b*128 + h
    const int j0  = (lid & 1) * 128;
    const size_t m0 = (size_t)bx * 128;
    const int bb = bx >> 7, hh = bx & 127;
    const int r = tid >> 1, half = tid & 1;    // A staging: row r, k-half
    const int idx0 = tid, idx1 = tid + 256;    // B staging 16B chunks

    // slot-XOR constants
    const int xr  = (r >> 2) & 3;
    const int sA0 = ((half * 2 + 0) ^ xr) * 8;
    const int sA1 = ((half * 2 + 1) ^ xr) * 8;
    const int bxo0 = ((idx0 & 3) ^ ((idx0 >> 4) & 3)) * 8;
    const int bxo1 = ((idx1 & 3) ^ ((idx1 >> 4) & 3)) * 8;
    const size_t bro0 = (size_t)(j0 + (idx0 >> 2)) * Cc;
    const size_t bro1 = (size_t)(j0 + (idx1 >> 2)) * Cc;

    float4 av0[4], av1[4];

    auto loadA = [&](int t, float4* av) {
        const int kb = t * 32 + half * 16;
#pragma unroll
        for (int j = 0; j < 4; ++j) {
            const int c  = kb + j * 4;
            const int s  = c / CSZ - SPAD;
            const int hs = hh - s;
            av[j] = make_float4(0.f, 0.f, 0.f, 0.f);
            if (hs >= 0 && hs < Hc)
                av[j] = *(const float4*)(x + ((size_t)(bb * Nc + hs * Wc + r)) * Cc + c);
        }
    };
    auto storeA = [&](int buf, const float4* av) {
        uint4 q0, q1;
        q0.x = pk2bf(av[0].x, av[0].y); q0.y = pk2bf(av[0].z, av[0].w);
        q0.z = pk2bf(av[1].x, av[1].y); q0.w = pk2bf(av[1].z, av[1].w);
        q1.x = pk2bf(av[2].x, av[2].y); q1.y = pk2bf(av[2].z, av[2].w);
        q1.z = pk2bf(av[3].x, av[3].y); q1.w = pk2bf(av[3].z, av[3].w);
        __bf16* base = As + buf * 4096 + r * 32;
        *(uint4*)(base + sA0) = q0;
        *(uint4*)(base + sA1) = q1;
    };
    auto stageB = [&](int buf, int t) {
        const int k0 = t * 32;
        __bf16* bdst = Bs + buf * 4096;
        async16(w1b + bro0 + k0 + bxo0, bdst + idx0 * 8);
        async16(w1b + bro1 + k0 + bxo1, bdst + idx1 * 8);
    };

    f32x4 acc[4][4] = {};
    const int kq  = (lane >> 4) * 8;
    const int kqx = kq ^ (((lane >> 2) & 3) << 3);
    const int rr  = lane & 15;

    // prologue: A(0),B(0),B(1),A(1) in flight; store A(0); keep B(1)+A(1) flying.
    loadA(0, av0);
    stageB(0, 0);
    stageB(1, 1);
    loadA(1, av1);
    storeA(0, av0);
    FENCE(6);

#define F1_STEP(T, AVL, AVS, FN)                                              \
    {                                                                          \
        if constexpr ((T) <= 5) { loadA((T) + 2, AVL); stageB(((T) + 2) % 3, (T) + 2); } \
        bf16x8 a[4], b[4];                                                     \
        const __bf16* ap = As + ((T) & 1) * 4096;                              \
        const __bf16* bp = Bs + ((T) % 3) * 4096;                              \
        _Pragma("unroll")                                                      \
        for (int i = 0; i < 4; ++i) {                                          \
            a[i] = *(const bf16x8*)(ap + (wm + i * 16 + rr) * 32 + kqx);       \
            b[i] = *(const bf16x8*)(bp + (wn + i * 16 + rr) * 32 + kqx);       \
        }                                                                      \
        _Pragma("unroll")                                                      \
        for (int i = 0; i < 4; ++i)                                            \
            _Pragma("unroll")                                                  \
            for (int j = 0; j < 4; ++j)                                        \
                acc[i][j] = __builtin_amdgcn_mfma_f32_16x16x32_bf16(a[i], b[j], acc[i][j], 0, 0, 0); \
        if constexpr ((T) <= 6) storeA(((T) + 1) & 1, AVS);                    \
        FN;                                                                    \
    }

    F1_STEP(0, av0, av1, FENCE(6));
    F1_STEP(1, av1, av0, FENCE(6));
    F1_STEP(2, av0, av1, FENCE(6));
    F1_STEP(3, av1, av0, FENCE(6));
    F1_STEP(4, av0, av1, FENCE(6));
    F1_STEP(5, av1, av0, FENCE(6));
    F1_STEP(6, av0, av1, FENCE(0));
    F1_STEP(7, av1, av0, FENCE(0));
#undef F1_STEP

    const int cq = (lane >> 4) * 4;
    const int cc = lane & 15;
    float bv[4];
#pragma unroll
    for (int j = 0; j < 4; ++j) bv[j] = b1[j0 + wn + j * 16 + cc];
#pragma unroll
    for (int i = 0; i < 4; ++i)
#pragma unroll
        for (int j = 0; j < 4; ++j) {
            const int col = wn + j * 16 + cc;
#pragma unroll
            for (int rg = 0; rg < 4; ++rg)
                Cs[(wm + i * 16 + cq + rg) * 136 + col] = f2bf(acc[i][j][rg] + bv[j]);
        }
    __syncthreads();
    {
        const int row = tid >> 1, hf = tid & 1;
        const unsigned short* src = Cs + row * 136 + hf * 64;
        unsigned short* dst = h1 + (m0 + row) * Cc + j0 + hf * 64;
#pragma unroll
        for (int i = 0; i < 8; ++i)
            *(uint4*)(dst + i * 8) = *(const uint4*)(src + i * 8);
    }
}

// ---------------------------------------------------------------------------
// border zeros for g_shifted: w in {0,1,126,127}, all channels.
// ---------------------------------------------------------------------------
__global__ __launch_bounds__(256)
void zero_borders_kernel(unsigned short* __restrict__ gsh)
{
    const int gid = blockIdx.x * 256 + threadIdx.x;   // 131072 total
    const int cg  = gid & 31;
    const int rest = gid >> 5;
    const int wi = rest & 3;
    const int bh = rest >> 2;                         // b*128 + h
    const int w  = (wi & 2) ? (wi + 124) : wi;        // 0,1,126,127
    uint4 z; z.x = z.y = z.z = z.w = 0u;
    *(uint4*)(gsh + ((size_t)bh * 128 + w) * Cc + cg * 8) = z;
}

// ---------------------------------------------------------------------------
// K2: depthwise 3x3 + bias + GELU(sigmoid-form) + W-shift scatter.
// 256 threads = 32 channel-groups (t&31) x 8 w-quads (t>>5).
// Block = quarter of one (b,h) row; grid.x = 4 * 1024.
// ---------------------------------------------------------------------------
__global__ __launch_bounds__(256)
void dwconv_gelu_scatter_kernel(const unsigned short* __restrict__ h1,
                                const float* __restrict__ dwT, const float* __restrict__ dw_b,
                                unsigned short* __restrict__ gsh)
{
    const int t   = threadIdx.x;
    const int cg  = t & 31;           // channel group (8 ch): covers 256 ch
    const int wq  = t >> 5;           // w-quad 0..7
    const int c0  = cg * 8;
    const int bh  = blockIdx.x >> 2;  // b*128 + h
    const int qtr = blockIdx.x & 3;   // quarter-row
    const int bb  = bh >> 7, hh = bh & 127;
    const size_t rowb = (size_t)bb * Nc + (size_t)hh * Wc;
    const int wbase = qtr * 32 + wq * 4 - 1;

    float acc[4][8];
    {
        float4 a0 = *(const float4*)(dw_b + c0);
        float4 a1 = *(const float4*)(dw_b + c0 + 4);
#pragma unroll
        for (int i = 0; i < 4; ++i) {
            acc[i][0] = a0.x; acc[i][1] = a0.y; acc[i][2] = a0.z; acc[i][3] = a0.w;
            acc[i][4] = a1.x; acc[i][5] = a1.y; acc[i][6] = a1.z; acc[i][7] = a1.w;
        }
    }

#pragma unroll
    for (int dy = -1; dy <= 1; ++dy) {
        const int y = hh + dy;
        if (y < 0 || y >= Hc) continue;          // block-uniform
        const unsigned short* rp = h1 + ((size_t)bb * Nc + (size_t)y * Wc) * Cc + c0;
        float in[6][8];
#pragma unroll
        for (int dx = 0; dx < 6; ++dx) {
            const int w = wbase + dx;
            ushort8 raw = {0, 0, 0, 0, 0, 0, 0, 0};
            if (w >= 0 && w < Wc) raw = *(const ushort8*)(rp + (size_t)w * Cc);
#pragma unroll
            for (int c = 0; c < 8; ++c) in[dx][c] = bf2f(raw[c]);
        }
        const float* wrow = dwT + (dy + 1) * 3 * Cc + c0;
        float wr[3][8];
#pragma unroll
        for (int tx = 0; tx < 3; ++tx) {
            float4 wa = *(const float4*)(wrow + tx * Cc);
            float4 wb = *(const float4*)(wrow + tx * Cc + 4);
            wr[tx][0] = wa.x; wr[tx][1] = wa.y; wr[tx][2] = wa.z; wr[tx][3] = wa.w;
            wr[tx][4] = wb.x; wr[tx][5] = wb.y; wr[tx][6] = wb.z; wr[tx][7] = wb.w;
        }
#pragma unroll
        for (int i = 0; i < 4; ++i)
#pragma unroll
            for (int tx = 0; tx < 3; ++tx)
#pragma unroll
                for (int c = 0; c < 8; ++c)
                    acc[i][c] += in[i + tx][c] * wr[tx][c];
    }

    const int s0 = c0 / CSZ - SPAD;
    const int s1 = (c0 + 4) / CSZ - SPAD;
#pragma unroll
    for (int i = 0; i < 4; ++i) {
        float g[8];
#pragma unroll
        for (int c = 0; c < 8; ++c) {
            const float v = acc[i][c];
            // gelu(v) ~= v * sigmoid(1.59576912*v + 0.07135482*v^3)
            const float u = v * v;
            const float a = __builtin_fmaf(0.0713548162f, u, 1.5957691216f);
            const float e = __expf(v * a);
            g[c] = v * e * __builtin_amdgcn_rcpf(e + 1.0f);
        }
        uint2 lo, hi;
        lo.x = pk2bf(g[0], g[1]); lo.y = pk2bf(g[2], g[3]);
        hi.x = pk2bf(g[4], g[5]); hi.y = pk2bf(g[6], g[7]);
        const int wo = wbase + 1 + i;
        const int w0 = wo + s0, w1 = wo + s1;
        if ((unsigned)w0 < (unsigned)Wc) *(uint2*)(gsh + (rowb + w0) * Cc + c0)     = lo;
        if ((unsigned)w1 < (unsigned)Wc) *(uint2*)(gsh + (rowb + w1) * Cc + c0 + 4) = hi;
    }
}

// ---------------------------------------------------------------------------
// K3: out = g_shifted @ w2^T + b2. Mirror of fc1's pipeline:
// A (gsh bf16) via async16 3-buffer 2 steps ahead (source-XOR);
// B (w2 fp32) reg-loaded at step top, packed+XOR-ds_written at step bottom
// (2-buffer). Counted vmcnt(2) fences. LDS 40960 -> 4 blocks/CU.
// ---------------------------------------------------------------------------
__global__ __launch_bounds__(256)
void fc2_mfma_kernel(const unsigned short* __restrict__ A, const float* __restrict__ w2,
                     const float* __restrict__ b2, float* __restrict__ out)
{
    __shared__ __align__(16) unsigned char smem[40960];
    __bf16* As = (__bf16*)smem;                  // [3][128][32] XOR via src
    __bf16* Bs = (__bf16*)(smem + 24576);        // [2][128][32] XOR-written

    const int tid  = threadIdx.x;
    const int lane = tid & 63;
    const int wave = tid >> 6;
    const int wm = (wave >> 1) * 64, wn = (wave & 1) * 64;

    const int lid = ((blockIdx.x & 7) << 8) | (blockIdx.x >> 3);
    const size_t m0 = (size_t)(lid >> 1) * 128;
    const int j0 = (lid & 1) * 128;

    const int idx0 = tid, idx1 = tid + 256;
    const int brow = tid >> 1, bhalf = tid & 1;

    const int axo0 = ((idx0 & 3) ^ ((idx0 >> 4) & 3)) * 8;
    const int axo1 = ((idx1 & 3) ^ ((idx1 >> 4) & 3)) * 8;
    const size_t aro0 = (m0 + (idx0 >> 2)) * Cc;
    const size_t aro1 = (m0 + (idx1 >> 2)) * Cc;
    const int xrB = (brow >> 2) & 3;
    const int sB0 = ((bhalf * 2 + 0) ^ xrB) * 8;
    const int sB1 = ((bhalf * 2 + 1) ^ xrB) * 8;

    float4 wv[4];
    auto loadB = [&](int t) {
        const float* src = w2 + (size_t)(j0 + brow) * Cc + t * 32 + bhalf * 16;
        wv[0] = *(const float4*)(src);
        wv[1] = *(const float4*)(src + 4);
        wv[2] = *(const float4*)(src + 8);
        wv[3] = *(const float4*)(src + 12);
    };
    auto storeB = [&](int buf) {
        uint4 p0, p1;
        p0.x = pk2bf(wv[0].x, wv[0].y); p0.y = pk2bf(wv[0].z, wv[0].w);
        p0.z = pk2bf(wv[1].x, wv[1].y); p0.w = pk2bf(wv[1].z, wv[1].w);
        p1.x = pk2bf(wv[2].x, wv[2].y); p1.y = pk2bf(wv[2].z, wv[2].w);
        p1.z = pk2bf(wv[3].x, wv[3].y); p1.w = pk2bf(wv[3].z, wv[3].w);
        __bf16* base = Bs + buf * 4096 + brow * 32;
        *(uint4*)(base + sB0) = p0;
        *(uint4*)(base + sB1) = p1;
    };
    auto stageA = [&](int buf, int t) {
        const int k0 = t * 32;
        __bf16* adst = As + buf * 4096;
        async16(A + aro0 + k0 + axo0, adst + idx0 * 8);
        async16(A + aro1 + k0 + axo1, adst + idx1 * 8);
    };

    f32x4 acc[4][4] = {};
    const int kq  = (lane >> 4) * 8;
    const int kqx = kq ^ (((lane >> 2) & 3) << 3);
    const int rr  = lane & 15;

    // prologue
    loadB(0);
    stageA(0, 0);
    stageA(1, 1);
    storeB(0);       // implicit vmcnt(4): waits B(0); A(0),A(1) stay in flight
    FENCE(2);        // drain A(0); keep A(1)

#define F2_STEP(T, FN)                                                        \
    {                                                                          \
        if constexpr ((T) <= 6) loadB((T) + 1);                                \
        if constexpr ((T) <= 5) stageA(((T) + 2) % 3, (T) + 2);                \
        bf16x8 a[4], b[4];                                                     \
        const __bf16* ap = As + ((T) % 3) * 4096;                              \
        const __bf16* bp = Bs + ((T) & 1) * 4096;                              \
        _Pragma("unroll")                                                      \
        for (int i = 0; i < 4; ++i) {                                          \
            a[i] = *(const bf16x8*)(ap + (wm + i * 16 + rr) * 32 + kqx);       \
            b[i] = *(const bf16x8*)(bp + (wn + i * 16 + rr) * 32 + kqx);       \
        }                                                                      \
        _Pragma("unroll")                                                      \
        for (int i = 0; i < 4; ++i)                                            \
            _Pragma("unroll")                                                  \
            for (int j = 0; j < 4; ++j)                                        \
                acc[i][j] = __builtin_amdgcn_mfma_f32_16x16x32_bf16(a[i], b[j], acc[i][j], 0, 0, 0); \
        if constexpr ((T) <= 6) storeB(((T) + 1) & 1);                         \
        FN;                                                                    \
    }

    F2_STEP(0, FENCE(2));
    F2_STEP(1, FENCE(2));
    F2_STEP(2, FENCE(2));
    F2_STEP(3, FENCE(2));
    F2_STEP(4, FENCE(2));
    F2_STEP(5, FENCE(2));
    F2_STEP(6, FENCE(0));
    F2_STEP(7, FENCE(0));
#undef F2_STEP

    const int cq = (lane >> 4) * 4;
    const int cc = lane & 15;
    float bv[4];
#pragma unroll
    for (int j = 0; j < 4; ++j) bv[j] = b2[j0 + wn + j * 16 + cc];
#pragma unroll
    for (int i = 0; i < 4; ++i)
#pragma unroll
        for (int j = 0; j < 4; ++j) {
            const int col = j0 + wn + j * 16 + cc;
#pragma unroll
            for (int rg = 0; rg < 4; ++rg)
                out[(m0 + wm + i * 16 + cq + rg) * Cc + col] = acc[i][j][rg] + bv[j];
        }
}

extern "C" void kernel_launch(void* const* d_in, const int* in_sizes, int n_in,
                              void* d_out, int out_size, void* d_ws, size_t ws_size,
                              hipStream_t stream) {
    // inputs: x, H, W, w1, b1, dw_w, dw_b, w2, b2
    const float* x    = (const float*)d_in[0];
    const float* w1   = (const float*)d_in[3];
    const float* b1   = (const float*)d_in[4];
    const float* dw_w = (const float*)d_in[5];
    const float* dw_b = (const float*)d_in[6];
    const float* w2   = (const float*)d_in[7];
    const float* b2   = (const float*)d_in[8];
    float* out = (float*)d_out;

    // ws: [0,64MB) h1 bf16; [64MB,128MB) g_shifted bf16
    unsigned short* h1  = (unsigned short*)d_ws;
    unsigned short* gsh = h1 + (size_t)Mtot * Cc;
    // w1(bf16) + dwT(fp32) live in d_out's head: dead until fc2 fully
    // rewrites every element of out (fc1 reads w1b before any out write;
    // conv reads dwT before fc2 launches).
    unsigned short* w1b = (unsigned short*)d_out;          // 128 KB
    float*          dwT = (float*)(w1b + 65536);           // 9 KB

    wprep_kernel<<<dim3(64), dim3(256), 0, stream>>>(w1, dw_w, w1b, dwT);
    fc1_mfma_kernel<<<dim3(2 * Mtot / 128), dim3(256), 0, stream>>>(x, w1b, b1, h1);
    zero_borders_kernel<<<dim3(512), dim3(256), 0, stream>>>(gsh);
    dwconv_gelu_scatter_kernel<<<dim3(4 * Mtot / 128), dim3(256), 0, stream>>>(h1, dwT, dw_b, gsh);
    fc2_mfma_kernel<<<dim3(2 * Mtot / 128), dim3(256), 0, stream>>>(gsh, w2, b2, out);
}

// Round 4
// 357.938 us; speedup vs baseline: 1.0043x; 1.0043x over previous
//
#include <hip/hip_runtime.h>
#include <hip/hip_bf16.h>
#include <math.h>

// B=8, H=W=128, C=hidden=256, N=16384, Mtot=131072.
#define Hc   128
#define Wc   128
#define Cc   256
#define Nc   (Hc * Wc)
#define Bn   8
#define Mtot (Bn * Nc)          // 131072
#define CSZ  52                 // ceil(256/5)
#define SPAD 2

typedef unsigned short ushort4v __attribute__((ext_vector_type(4)));
typedef unsigned short ushort8  __attribute__((ext_vector_type(8)));
typedef __bf16         bf16x8   __attribute__((ext_vector_type(8)));
typedef float          f32x4    __attribute__((ext_vector_type(4)));

__device__ __forceinline__ float bf2f(unsigned short u) {
    return __uint_as_float(((unsigned)u) << 16);
}
__device__ __forceinline__ unsigned short f2bf(float f) {   // RNE
    unsigned u = __float_as_uint(f);
    return (unsigned short)((u + 0x7fffu + ((u >> 16) & 1u)) >> 16);
}
// pack two floats -> two bf16 (a -> low16). Round-half-up (ok vs bf16 eps).
__device__ __forceinline__ unsigned pk2bf(float a, float b) {
    unsigned ua = __float_as_uint(a) + 0x8000u;
    unsigned ub = __float_as_uint(b) + 0x8000u;
    return __builtin_amdgcn_perm(ub, ua, 0x07060302);
}
__device__ __forceinline__ void async16(const void* g, void* l) {
    __builtin_amdgcn_global_load_lds(
        (const __attribute__((address_space(1))) unsigned*)g,
        (__attribute__((address_space(3))) unsigned*)l, 16, 0, 0);
}

// Counted-vmcnt fence + raw barrier (fc2 only).
#define FENCE(vm) asm volatile("s_waitcnt vmcnt(" #vm ") lgkmcnt(0)\n\ts_barrier" ::: "memory")

// ---------------------------------------------------------------------------
// P0: w1 fp32 -> bf16 (into d_out head, dead until fc2 rewrites all of out);
//     dw_w [ch][tap] -> dwT [tap][ch] fp32.
// ---------------------------------------------------------------------------
__global__ __launch_bounds__(256)
void wprep_kernel(const float* __restrict__ w1, const float* __restrict__ dw_w,
                  unsigned short* __restrict__ w1b, float* __restrict__ dwT)
{
    const int g = blockIdx.x * 256 + threadIdx.x;   // 16384 threads
    {
        float4 a = *(const float4*)(w1 + (size_t)g * 4);
        ushort4v o = { f2bf(a.x), f2bf(a.y), f2bf(a.z), f2bf(a.w) };
        *(ushort4v*)(w1b + (size_t)g * 4) = o;
    }
    if (g < 9 * Cc) dwT[(g % 9) * Cc + g / 9] = dw_w[g];
}

// ---------------------------------------------------------------------------
// P1: H-shift + fp32->bf16 convert, gather form: xb[(b,h,w)][c] =
// (0 <= h - s_c < H) ? bf16(x[(b, h-s_c, w)][c]) : 0.   s_c = c/52 - 2.
// One float4 (4 ch) per thread per iter: 52 % 4 == 0, so a float4 never
// crosses a shift boundary. Lanes sweep c fastest -> both read and write
// fully coalesced (1 KB per wave-instr read, 512 B write).
// xb lives in the gsh region: dead until fc1 finishes (stream-serial).
// ---------------------------------------------------------------------------
__global__ __launch_bounds__(256)
void shiftcvt_kernel(const float* __restrict__ x, unsigned short* __restrict__ xb)
{
    const int gid0 = blockIdx.x * 256 + threadIdx.x;
#pragma unroll
    for (int it = 0; it < 4; ++it) {
        const int gid = gid0 + it * (8192 * 256);   // 8.39M chunks total
        const int row = gid >> 6;                   // b*16384 + h*128 + w
        const int c   = (gid & 63) * 4;
        const int hh  = (row >> 7) & 127;
        const int s   = c / CSZ - SPAD;
        const int hs  = hh - s;
        float4 v = make_float4(0.f, 0.f, 0.f, 0.f);
        if (hs >= 0 && hs < Hc)
            v = *(const float4*)(x + ((size_t)row + (size_t)(hs - hh) * Wc) * Cc + c);
        uint2 o; o.x = pk2bf(v.x, v.y); o.y = pk2bf(v.z, v.w);
        *(uint2*)(xb + (size_t)row * Cc + c) = o;
    }
}

// ---------------------------------------------------------------------------
// K1: h1 = x_shifted_bf16 @ w1^T + b1. Pure bf16 GEMM: BOTH panels staged
// via async16 (zero staging VALU / zero staging registers). 128x128 tile,
// BK=32, 16x16x32 MFMA, r2-style single-barrier 1-step-lookahead pipeline.
// LDS 34816 B (A/B double-buf 32 KB; Cs epilogue unions) -> 4 blocks/CU.
// XCD-bijective swizzle keeps the column-tile pair adjacent on one XCD.
// ---------------------------------------------------------------------------
__global__ __launch_bounds__(256)
void fc1_mfma_kernel(const unsigned short* __restrict__ xb, const unsigned short* __restrict__ w1b,
                     const float* __restrict__ b1, unsigned short* __restrict__ h1)
{
    __shared__ __align__(16) unsigned char smem[34816];
    __bf16* As = (__bf16*)smem;                     // [2][128][32]
    __bf16* Bs = (__bf16*)(smem + 16384);           // [2][128][32]
    unsigned short* Cs = (unsigned short*)smem;     // [128][136] epilogue

    const int tid  = threadIdx.x;
    const int lane = tid & 63;
    const int wave = tid >> 6;
    const int wm = (wave >> 1) * 64, wn = (wave & 1) * 64;

    // nwg = 2048 (div by 8): bijective XCD swizzle.
    const int lid = ((blockIdx.x & 7) << 8) | (blockIdx.x >> 3);
    const int bx  = lid >> 1;                  // b*128 + h
    const int j0  = (lid & 1) * 128;
    const size_t m0 = (size_t)bx * 128;
    const int idx0 = tid, idx1 = tid + 256;    // 16B chunks per panel

    const size_t aro0 = (m0 + (idx0 >> 2)) * Cc + (idx0 & 3) * 8;
    const size_t aro1 = (m0 + (idx1 >> 2)) * Cc + (idx1 & 3) * 8;
    const size_t bro0 = (size_t)(j0 + (idx0 >> 2)) * Cc + (idx0 & 3) * 8;
    const size_t bro1 = (size_t)(j0 + (idx1 >> 2)) * Cc + (idx1 & 3) * 8;

    auto stage = [&](int buf, int t) {
        const int k0 = t * 32;
        __bf16* adst = As + buf * 4096;
        __bf16* bdst = Bs + buf * 4096;
        async16(xb  + aro0 + k0, adst + idx0 * 8);
        async16(xb  + aro1 + k0, adst + idx1 * 8);
        async16(w1b + bro0 + k0, bdst + idx0 * 8);
        async16(w1b + bro1 + k0, bdst + idx1 * 8);
    };

    f32x4 acc[4][4] = {};
    const int kq = (lane >> 4) * 8;
    const int rr = lane & 15;

    stage(0, 0);
    __syncthreads();

    int cur = 0;
    for (int t = 0; t < 8; ++t) {
        const int nxt = cur ^ 1;
        if (t < 7) stage(nxt, t + 1);   // issue next tile BEFORE compute
        bf16x8 a[4], b[4];
        const __bf16* ap = As + cur * 4096;
        const __bf16* bp = Bs + cur * 4096;
#pragma unroll
        for (int i = 0; i < 4; ++i) {
            a[i] = *(const bf16x8*)(ap + (wm + i * 16 + rr) * 32 + kq);
            b[i] = *(const bf16x8*)(bp + (wn + i * 16 + rr) * 32 + kq);
        }
#pragma unroll
        for (int i = 0; i < 4; ++i)
#pragma unroll
            for (int j = 0; j < 4; ++j)
                acc[i][j] = __builtin_amdgcn_mfma_f32_16x16x32_bf16(a[i], b[j], acc[i][j], 0, 0, 0);
        __syncthreads();                // drains next-tile loads (m97 structure)
        cur = nxt;
    }

    const int cq = (lane >> 4) * 4;
    const int cc = lane & 15;
    float bv[4];
#pragma unroll
    for (int j = 0; j < 4; ++j) bv[j] = b1[j0 + wn + j * 16 + cc];
#pragma unroll
    for (int i = 0; i < 4; ++i)
#pragma unroll
        for (int j = 0; j < 4; ++j) {
            const int col = wn + j * 16 + cc;
#pragma unroll
            for (int rg = 0; rg < 4; ++rg)
                Cs[(wm + i * 16 + cq + rg) * 136 + col] = f2bf(acc[i][j][rg] + bv[j]);
        }
    __syncthreads();
    {
        const int row = tid >> 1, hf = tid & 1;
        const unsigned short* src = Cs + row * 136 + hf * 64;
        unsigned short* dst = h1 + (m0 + row) * Cc + j0 + hf * 64;
#pragma unroll
        for (int i = 0; i < 8; ++i)
            *(uint4*)(dst + i * 8) = *(const uint4*)(src + i * 8);
    }
}

// ---------------------------------------------------------------------------
// border zeros for g_shifted: w in {0,1,126,127}, all channels.
// ---------------------------------------------------------------------------
__global__ __launch_bounds__(256)
void zero_borders_kernel(unsigned short* __restrict__ gsh)
{
    const int gid = blockIdx.x * 256 + threadIdx.x;   // 131072 total
    const int cg  = gid & 31;
    const int rest = gid >> 5;
    const int wi = rest & 3;
    const int bh = rest >> 2;                         // b*128 + h
    const int w  = (wi & 2) ? (wi + 124) : wi;        // 0,1,126,127
    uint4 z; z.x = z.y = z.z = z.w = 0u;
    *(uint4*)(gsh + ((size_t)bh * 128 + w) * Cc + cg * 8) = z;
}

// ---------------------------------------------------------------------------
// K2: depthwise 3x3 + bias + GELU(sigmoid-form) + W-shift scatter.
// 256 threads = 32 channel-groups (t&31) x 8 w-quads (t>>5).
// Block = quarter of one (b,h) row; grid.x = 4 * 1024.
// ---------------------------------------------------------------------------
__global__ __launch_bounds__(256)
void dwconv_gelu_scatter_kernel(const unsigned short* __restrict__ h1,
                                const float* __restrict__ dwT, const float* __restrict__ dw_b,
                                unsigned short* __restrict__ gsh)
{
    const int t   = threadIdx.x;
    const int cg  = t & 31;           // channel group (8 ch): covers 256 ch
    const int wq  = t >> 5;           // w-quad 0..7
    const int c0  = cg * 8;
    const int bh  = blockIdx.x >> 2;  // b*128 + h
    const int qtr = blockIdx.x & 3;   // quarter-row
    const int bb  = bh >> 7, hh = bh & 127;
    const size_t rowb = (size_t)bb * Nc + (size_t)hh * Wc;
    const int wbase = qtr * 32 + wq * 4 - 1;

    float acc[4][8];
    {
        float4 a0 = *(const float4*)(dw_b + c0);
        float4 a1 = *(const float4*)(dw_b + c0 + 4);
#pragma unroll
        for (int i = 0; i < 4; ++i) {
            acc[i][0] = a0.x; acc[i][1] = a0.y; acc[i][2] = a0.z; acc[i][3] = a0.w;
            acc[i][4] = a1.x; acc[i][5] = a1.y; acc[i][6] = a1.z; acc[i][7] = a1.w;
        }
    }

#pragma unroll
    for (int dy = -1; dy <= 1; ++dy) {
        const int y = hh + dy;
        if (y < 0 || y >= Hc) continue;          // block-uniform
        const unsigned short* rp = h1 + ((size_t)bb * Nc + (size_t)y * Wc) * Cc + c0;
        float in[6][8];
#pragma unroll
        for (int dx = 0; dx < 6; ++dx) {
            const int w = wbase + dx;
            ushort8 raw = {0, 0, 0, 0, 0, 0, 0, 0};
            if (w >= 0 && w < Wc) raw = *(const ushort8*)(rp + (size_t)w * Cc);
#pragma unroll
            for (int c = 0; c < 8; ++c) in[dx][c] = bf2f(raw[c]);
        }
        const float* wrow = dwT + (dy + 1) * 3 * Cc + c0;
        float wr[3][8];
#pragma unroll
        for (int tx = 0; tx < 3; ++tx) {
            float4 wa = *(const float4*)(wrow + tx * Cc);
            float4 wb = *(const float4*)(wrow + tx * Cc + 4);
            wr[tx][0] = wa.x; wr[tx][1] = wa.y; wr[tx][2] = wa.z; wr[tx][3] = wa.w;
            wr[tx][4] = wb.x; wr[tx][5] = wb.y; wr[tx][6] = wb.z; wr[tx][7] = wb.w;
        }
#pragma unroll
        for (int i = 0; i < 4; ++i)
#pragma unroll
            for (int tx = 0; tx < 3; ++tx)
#pragma unroll
                for (int c = 0; c < 8; ++c)
                    acc[i][c] += in[i + tx][c] * wr[tx][c];
    }

    const int s0 = c0 / CSZ - SPAD;
    const int s1 = (c0 + 4) / CSZ - SPAD;
#pragma unroll
    for (int i = 0; i < 4; ++i) {
        float g[8];
#pragma unroll
        for (int c = 0; c < 8; ++c) {
            const float v = acc[i][c];
            // gelu(v) ~= v * sigmoid(1.59576912*v + 0.07135482*v^3)
            const float u = v * v;
            const float a = __builtin_fmaf(0.0713548162f, u, 1.5957691216f);
            const float e = __expf(v * a);
            g[c] = v * e * __builtin_amdgcn_rcpf(e + 1.0f);
        }
        uint2 lo, hi;
        lo.x = pk2bf(g[0], g[1]); lo.y = pk2bf(g[2], g[3]);
        hi.x = pk2bf(g[4], g[5]); hi.y = pk2bf(g[6], g[7]);
        const int wo = wbase + 1 + i;
        const int w0 = wo + s0, w1 = wo + s1;
        if ((unsigned)w0 < (unsigned)Wc) *(uint2*)(gsh + (rowb + w0) * Cc + c0)     = lo;
        if ((unsigned)w1 < (unsigned)Wc) *(uint2*)(gsh + (rowb + w1) * Cc + c0 + 4) = hi;
    }
}

// ---------------------------------------------------------------------------
// K3: out = g_shifted @ w2^T + b2. A (gsh bf16) via async16 3-buffer
// 2 steps ahead; B (w2 fp32) reg-loaded, packed+ds_written (2-buffer).
// Counted vmcnt(2) fences. LDS 40960.
// ---------------------------------------------------------------------------
__global__ __launch_bounds__(256)
void fc2_mfma_kernel(const unsigned short* __restrict__ A, const float* __restrict__ w2,
                     const float* __restrict__ b2, float* __restrict__ out)
{
    __shared__ __align__(16) unsigned char smem[40960];
    __bf16* As = (__bf16*)smem;                  // [3][128][32] via async16
    __bf16* Bs = (__bf16*)(smem + 24576);        // [2][128][32] XOR-written

    const int tid  = threadIdx.x;
    const int lane = tid & 63;
    const int wave = tid >> 6;
    const int wm = (wave >> 1) * 64, wn = (wave & 1) * 64;

    const int lid = ((blockIdx.x & 7) << 8) | (blockIdx.x >> 3);
    const size_t m0 = (size_t)(lid >> 1) * 128;
    const int j0 = (lid & 1) * 128;

    const int idx0 = tid, idx1 = tid + 256;
    const int brow = tid >> 1, bhalf = tid & 1;

    const int axo0 = ((idx0 & 3) ^ ((idx0 >> 4) & 3)) * 8;
    const int axo1 = ((idx1 & 3) ^ ((idx1 >> 4) & 3)) * 8;
    const size_t aro0 = (m0 + (idx0 >> 2)) * Cc;
    const size_t aro1 = (m0 + (idx1 >> 2)) * Cc;
    const int xrB = (brow >> 2) & 3;
    const int sB0 = ((bhalf * 2 + 0) ^ xrB) * 8;
    const int sB1 = ((bhalf * 2 + 1) ^ xrB) * 8;

    float4 wv[4];
    auto loadB = [&](int t) {
        const float* src = w2 + (size_t)(j0 + brow) * Cc + t * 32 + bhalf * 16;
        wv[0] = *(const float4*)(src);
        wv[1] = *(const float4*)(src + 4);
        wv[2] = *(const float4*)(src + 8);
        wv[3] = *(const float4*)(src + 12);
    };
    auto storeB = [&](int buf) {
        uint4 p0, p1;
        p0.x = pk2bf(wv[0].x, wv[0].y); p0.y = pk2bf(wv[0].z, wv[0].w);
        p0.z = pk2bf(wv[1].x, wv[1].y); p0.w = pk2bf(wv[1].z, wv[1].w);
        p1.x = pk2bf(wv[2].x, wv[2].y); p1.y = pk2bf(wv[2].z, wv[2].w);
        p1.z = pk2bf(wv[3].x, wv[3].y); p1.w = pk2bf(wv[3].z, wv[3].w);
        __bf16* base = Bs + buf * 4096 + brow * 32;
        *(uint4*)(base + sB0) = p0;
        *(uint4*)(base + sB1) = p1;
    };
    auto stageA = [&](int buf, int t) {
        const int k0 = t * 32;
        __bf16* adst = As + buf * 4096;
        async16(A + aro0 + k0 + axo0, adst + idx0 * 8);
        async16(A + aro1 + k0 + axo1, adst + idx1 * 8);
    };

    f32x4 acc[4][4] = {};
    const int kq  = (lane >> 4) * 8;
    const int kqx = kq ^ (((lane >> 2) & 3) << 3);
    const int rr  = lane & 15;

    // prologue
    loadB(0);
    stageA(0, 0);
    stageA(1, 1);
    storeB(0);       // implicit vmcnt(4): waits B(0); A(0),A(1) stay in flight
    FENCE(2);        // drain A(0); keep A(1)

#define F2_STEP(T, FN)                                                        \
    {                                                                          \
        if constexpr ((T) <= 6) loadB((T) + 1);                                \
        if constexpr ((T) <= 5) stageA(((T) + 2) % 3, (T) + 2);                \
        bf16x8 a[4], b[4];                                                     \
        const __bf16* ap = As + ((T) % 3) * 4096;                              \
        const __bf16* bp = Bs + ((T) & 1) * 4096;                              \
        _Pragma("unroll")                                                      \
        for (int i = 0; i < 4; ++i) {                                          \
            a[i] = *(const bf16x8*)(ap + (wm + i * 16 + rr) * 32 + kqx);       \
            b[i] = *(const bf16x8*)(bp + (wn + i * 16 + rr) * 32 + kqx);       \
        }                                                                      \
        _Pragma("unroll")                                                      \
        for (int i = 0; i < 4; ++i)                                            \
            _Pragma("unroll")                                                  \
            for (int j = 0; j < 4; ++j)                                        \
                acc[i][j] = __builtin_amdgcn_mfma_f32_16x16x32_bf16(a[i], b[j], acc[i][j], 0, 0, 0); \
        if constexpr ((T) <= 6) storeB(((T) + 1) & 1);                         \
        FN;                                                                    \
    }

    F2_STEP(0, FENCE(2));
    F2_STEP(1, FENCE(2));
    F2_STEP(2, FENCE(2));
    F2_STEP(3, FENCE(2));
    F2_STEP(4, FENCE(2));
    F2_STEP(5, FENCE(2));
    F2_STEP(6, FENCE(0));
    F2_STEP(7, FENCE(0));
#undef F2_STEP

    const int cq = (lane >> 4) * 4;
    const int cc = lane & 15;
    float bv[4];
#pragma unroll
    for (int j = 0; j < 4; ++j) bv[j] = b2[j0 + wn + j * 16 + cc];
#pragma unroll
    for (int i = 0; i < 4; ++i)
#pragma unroll
        for (int j = 0; j < 4; ++j) {
            const int col = j0 + wn + j * 16 + cc;
#pragma unroll
            for (int rg = 0; rg < 4; ++rg)
                out[(m0 + wm + i * 16 + cq + rg) * Cc + col] = acc[i][j][rg] + bv[j];
        }
}

extern "C" void kernel_launch(void* const* d_in, const int* in_sizes, int n_in,
                              void* d_out, int out_size, void* d_ws, size_t ws_size,
                              hipStream_t stream) {
    // inputs: x, H, W, w1, b1, dw_w, dw_b, w2, b2
    const float* x    = (const float*)d_in[0];
    const float* w1   = (const float*)d_in[3];
    const float* b1   = (const float*)d_in[4];
    const float* dw_w = (const float*)d_in[5];
    const float* dw_b = (const float*)d_in[6];
    const float* w2   = (const float*)d_in[7];
    const float* b2   = (const float*)d_in[8];
    float* out = (float*)d_out;

    // ws: [0,64MB) h1 bf16; [64MB,128MB) gsh bf16.
    // The gsh region double-serves as x_bf16 (shiftcvt output): fc1 fully
    // consumes it before zero_borders/dwconv overwrite the region (stream-
    // serial kernel order).
    unsigned short* h1  = (unsigned short*)d_ws;
    unsigned short* gsh = h1 + (size_t)Mtot * Cc;
    // w1(bf16) + dwT(fp32) live in d_out's head: dead until fc2 fully
    // rewrites every element of out.
    unsigned short* w1b = (unsigned short*)d_out;          // 128 KB
    float*          dwT = (float*)(w1b + 65536);           // 9 KB

    wprep_kernel<<<dim3(64), dim3(256), 0, stream>>>(w1, dw_w, w1b, dwT);
    shiftcvt_kernel<<<dim3(8192), dim3(256), 0, stream>>>(x, gsh);
    fc1_mfma_kernel<<<dim3(2 * Mtot / 128), dim3(256), 0, stream>>>(gsh, w1b, b1, h1);
    zero_borders_kernel<<<dim3(512), dim3(256), 0, stream>>>(gsh);
    dwconv_gelu_scatter_kernel<<<dim3(4 * Mtot / 128), dim3(256), 0, stream>>>(h1, dwT, dw_b, gsh);
    fc2_mfma_kernel<<<dim3(2 * Mtot / 128), dim3(256), 0, stream>>>(gsh, w2, b2, out);
}

// Round 5
// 354.607 us; speedup vs baseline: 1.0137x; 1.0094x over previous
//
#include <hip/hip_runtime.h>
#include <hip/hip_bf16.h>
#include <math.h>

// B=8, H=W=128, C=hidden=256, N=16384, Mtot=131072.
#define Hc   128
#define Wc   128
#define Cc   256
#define Nc   (Hc * Wc)
#define Bn   8
#define Mtot (Bn * Nc)          // 131072
#define CSZ  52                 // ceil(256/5)
#define SPAD 2

typedef unsigned short ushort4v __attribute__((ext_vector_type(4)));
typedef unsigned short ushort8  __attribute__((ext_vector_type(8)));
typedef __bf16         bf16x8   __attribute__((ext_vector_type(8)));
typedef float          f32x4    __attribute__((ext_vector_type(4)));

__device__ __forceinline__ float bf2f(unsigned short u) {
    return __uint_as_float(((unsigned)u) << 16);
}
__device__ __forceinline__ unsigned short f2bf(float f) {   // RNE
    unsigned u = __float_as_uint(f);
    return (unsigned short)((u + 0x7fffu + ((u >> 16) & 1u)) >> 16);
}
// pack two floats -> two bf16 (a -> low16). Round-half-up (ok vs bf16 eps).
__device__ __forceinline__ unsigned pk2bf(float a, float b) {
    unsigned ua = __float_as_uint(a) + 0x8000u;
    unsigned ub = __float_as_uint(b) + 0x8000u;
    return __builtin_amdgcn_perm(ub, ua, 0x07060302);
}
__device__ __forceinline__ void async16(const void* g, void* l) {
    __builtin_amdgcn_global_load_lds(
        (const __attribute__((address_space(1))) unsigned*)g,
        (__attribute__((address_space(3))) unsigned*)l, 16, 0, 0);
}

// ---------------------------------------------------------------------------
// P0: w1, w2 fp32 -> bf16; dw_w [ch][tap] -> dwT [tap][ch] fp32.
// All prep outputs live in d_ws (past the 128 MB h1/gsh region).
// ---------------------------------------------------------------------------
__global__ __launch_bounds__(256)
void wprep_kernel(const float* __restrict__ w1, const float* __restrict__ w2,
                  const float* __restrict__ dw_w,
                  unsigned short* __restrict__ w1b, unsigned short* __restrict__ w2b,
                  float* __restrict__ dwT)
{
    const int g = blockIdx.x * 256 + threadIdx.x;   // 16384 threads
    {
        float4 a = *(const float4*)(w1 + (size_t)g * 4);
        ushort4v o = { f2bf(a.x), f2bf(a.y), f2bf(a.z), f2bf(a.w) };
        *(ushort4v*)(w1b + (size_t)g * 4) = o;
    }
    {
        float4 a = *(const float4*)(w2 + (size_t)g * 4);
        ushort4v o = { f2bf(a.x), f2bf(a.y), f2bf(a.z), f2bf(a.w) };
        *(ushort4v*)(w2b + (size_t)g * 4) = o;
    }
    if (g < 9 * Cc) dwT[(g % 9) * Cc + g / 9] = dw_w[g];
}

// ---------------------------------------------------------------------------
// P1: H-shift + fp32->bf16 convert, gather form: xb[(b,h,w)][c] =
// (0 <= h - s_c < H) ? bf16(x[(b, h-s_c, w)][c]) : 0.   s_c = c/52 - 2.
// 8 channels/thread (two float4 loads, independent shifts for the two
// halves since a 4-chunk never crosses a 52-boundary) -> one uint4 store.
// Lanes sweep c fastest: writes 1 KB/wave contiguous; reads split into at
// most ~6 segments per wave (5 shift groups). xb lives in the gsh region
// (dead until fc1 finishes; stream-serial).
// ---------------------------------------------------------------------------
__global__ __launch_bounds__(256)
void shiftcvt_kernel(const float* __restrict__ x, unsigned short* __restrict__ xb)
{
    const int gid0 = blockIdx.x * 256 + threadIdx.x;
#pragma unroll
    for (int it = 0; it < 4; ++it) {
        const int gid = gid0 + it * (4096 * 256);   // 4.19M chunks total
        const int row = gid >> 5;                   // b*16384 + h*128 + w
        const int c   = (gid & 31) * 8;
        const int hh  = (row >> 7) & 127;
        const int s0  = c / CSZ - SPAD;
        const int s1  = (c + 4) / CSZ - SPAD;
        const int h0  = hh - s0, h1r = hh - s1;
        float4 v0 = make_float4(0.f, 0.f, 0.f, 0.f);
        float4 v1 = make_float4(0.f, 0.f, 0.f, 0.f);
        if (h0  >= 0 && h0  < Hc)
            v0 = *(const float4*)(x + ((size_t)row + (size_t)(h0 - hh) * Wc) * Cc + c);
        if (h1r >= 0 && h1r < Hc)
            v1 = *(const float4*)(x + ((size_t)row + (size_t)(h1r - hh) * Wc) * Cc + c + 4);
        uint4 o;
        o.x = pk2bf(v0.x, v0.y); o.y = pk2bf(v0.z, v0.w);
        o.z = pk2bf(v1.x, v1.y); o.w = pk2bf(v1.z, v1.w);
        *(uint4*)(xb + (size_t)row * Cc + c) = o;
    }
}

// ---------------------------------------------------------------------------
// K1: h1 = x_shifted_bf16 @ w1^T + b1. Pure bf16 GEMM: BOTH panels staged
// via async16 (zero staging VALU / zero staging registers). 128x128 tile,
// BK=32, 16x16x32 MFMA, single-barrier 1-step-lookahead pipeline.
// LDS 34816 B (A/B double-buf 32 KB; Cs epilogue unions) -> 4 blocks/CU.
// XCD-bijective swizzle keeps the column-tile pair adjacent on one XCD.
// ---------------------------------------------------------------------------
__global__ __launch_bounds__(256)
void fc1_mfma_kernel(const unsigned short* __restrict__ xb, const unsigned short* __restrict__ w1b,
                     const float* __restrict__ b1, unsigned short* __restrict__ h1)
{
    __shared__ __align__(16) unsigned char smem[34816];
    __bf16* As = (__bf16*)smem;                     // [2][128][32]
    __bf16* Bs = (__bf16*)(smem + 16384);           // [2][128][32]
    unsigned short* Cs = (unsigned short*)smem;     // [128][136] epilogue

    const int tid  = threadIdx.x;
    const int lane = tid & 63;
    const int wave = tid >> 6;
    const int wm = (wave >> 1) * 64, wn = (wave & 1) * 64;

    // nwg = 2048 (div by 8): bijective XCD swizzle.
    const int lid = ((blockIdx.x & 7) << 8) | (blockIdx.x >> 3);
    const int bx  = lid >> 1;                  // b*128 + h
    const int j0  = (lid & 1) * 128;
    const size_t m0 = (size_t)bx * 128;
    const int idx0 = tid, idx1 = tid + 256;    // 16B chunks per panel

    const size_t aro0 = (m0 + (idx0 >> 2)) * Cc + (idx0 & 3) * 8;
    const size_t aro1 = (m0 + (idx1 >> 2)) * Cc + (idx1 & 3) * 8;
    const size_t bro0 = (size_t)(j0 + (idx0 >> 2)) * Cc + (idx0 & 3) * 8;
    const size_t bro1 = (size_t)(j0 + (idx1 >> 2)) * Cc + (idx1 & 3) * 8;

    auto stage = [&](int buf, int t) {
        const int k0 = t * 32;
        __bf16* adst = As + buf * 4096;
        __bf16* bdst = Bs + buf * 4096;
        async16(xb  + aro0 + k0, adst + idx0 * 8);
        async16(xb  + aro1 + k0, adst + idx1 * 8);
        async16(w1b + bro0 + k0, bdst + idx0 * 8);
        async16(w1b + bro1 + k0, bdst + idx1 * 8);
    };

    f32x4 acc[4][4] = {};
    const int kq = (lane >> 4) * 8;
    const int rr = lane & 15;

    stage(0, 0);
    __syncthreads();

    int cur = 0;
    for (int t = 0; t < 8; ++t) {
        const int nxt = cur ^ 1;
        if (t < 7) stage(nxt, t + 1);   // issue next tile BEFORE compute
        bf16x8 a[4], b[4];
        const __bf16* ap = As + cur * 4096;
        const __bf16* bp = Bs + cur * 4096;
#pragma unroll
        for (int i = 0; i < 4; ++i) {
            a[i] = *(const bf16x8*)(ap + (wm + i * 16 + rr) * 32 + kq);
            b[i] = *(const bf16x8*)(bp + (wn + i * 16 + rr) * 32 + kq);
        }
#pragma unroll
        for (int i = 0; i < 4; ++i)
#pragma unroll
            for (int j = 0; j < 4; ++j)
                acc[i][j] = __builtin_amdgcn_mfma_f32_16x16x32_bf16(a[i], b[j], acc[i][j], 0, 0, 0);
        __syncthreads();                // drains next-tile loads (m97 structure)
        cur = nxt;
    }

    const int cq = (lane >> 4) * 4;
    const int cc = lane & 15;
    float bv[4];
#pragma unroll
    for (int j = 0; j < 4; ++j) bv[j] = b1[j0 + wn + j * 16 + cc];
#pragma unroll
    for (int i = 0; i < 4; ++i)
#pragma unroll
        for (int j = 0; j < 4; ++j) {
            const int col = wn + j * 16 + cc;
#pragma unroll
            for (int rg = 0; rg < 4; ++rg)
                Cs[(wm + i * 16 + cq + rg) * 136 + col] = f2bf(acc[i][j][rg] + bv[j]);
        }
    __syncthreads();
    {
        const int row = tid >> 1, hf = tid & 1;
        const unsigned short* src = Cs + row * 136 + hf * 64;
        unsigned short* dst = h1 + (m0 + row) * Cc + j0 + hf * 64;
#pragma unroll
        for (int i = 0; i < 8; ++i)
            *(uint4*)(dst + i * 8) = *(const uint4*)(src + i * 8);
    }
}

// ---------------------------------------------------------------------------
// border zeros for g_shifted: w in {0,1,126,127}, all channels.
// ---------------------------------------------------------------------------
__global__ __launch_bounds__(256)
void zero_borders_kernel(unsigned short* __restrict__ gsh)
{
    const int gid = blockIdx.x * 256 + threadIdx.x;   // 131072 total
    const int cg  = gid & 31;
    const int rest = gid >> 5;
    const int wi = rest & 3;
    const int bh = rest >> 2;                         // b*128 + h
    const int w  = (wi & 2) ? (wi + 124) : wi;        // 0,1,126,127
    uint4 z; z.x = z.y = z.z = z.w = 0u;
    *(uint4*)(gsh + ((size_t)bh * 128 + w) * Cc + cg * 8) = z;
}

// ---------------------------------------------------------------------------
// K2: depthwise 3x3 + bias + GELU(sigmoid-form) + W-shift scatter.
// 256 threads = 32 channel-groups (t&31) x 8 w-quads (t>>5).
// Block = quarter of one (b,h) row; grid.x = 4 * 1024.
// ---------------------------------------------------------------------------
__global__ __launch_bounds__(256)
void dwconv_gelu_scatter_kernel(const unsigned short* __restrict__ h1,
                                const float* __restrict__ dwT, const float* __restrict__ dw_b,
                                unsigned short* __restrict__ gsh)
{
    const int t   = threadIdx.x;
    const int cg  = t & 31;           // channel group (8 ch): covers 256 ch
    const int wq  = t >> 5;           // w-quad 0..7
    const int c0  = cg * 8;
    const int bh  = blockIdx.x >> 2;  // b*128 + h
    const int qtr = blockIdx.x & 3;   // quarter-row
    const int bb  = bh >> 7, hh = bh & 127;
    const size_t rowb = (size_t)bb * Nc + (size_t)hh * Wc;
    const int wbase = qtr * 32 + wq * 4 - 1;

    float acc[4][8];
    {
        float4 a0 = *(const float4*)(dw_b + c0);
        float4 a1 = *(const float4*)(dw_b + c0 + 4);
#pragma unroll
        for (int i = 0; i < 4; ++i) {
            acc[i][0] = a0.x; acc[i][1] = a0.y; acc[i][2] = a0.z; acc[i][3] = a0.w;
            acc[i][4] = a1.x; acc[i][5] = a1.y; acc[i][6] = a1.z; acc[i][7] = a1.w;
        }
    }

#pragma unroll
    for (int dy = -1; dy <= 1; ++dy) {
        const int y = hh + dy;
        if (y < 0 || y >= Hc) continue;          // block-uniform
        const unsigned short* rp = h1 + ((size_t)bb * Nc + (size_t)y * Wc) * Cc + c0;
        float in[6][8];
#pragma unroll
        for (int dx = 0; dx < 6; ++dx) {
            const int w = wbase + dx;
            ushort8 raw = {0, 0, 0, 0, 0, 0, 0, 0};
            if (w >= 0 && w < Wc) raw = *(const ushort8*)(rp + (size_t)w * Cc);
#pragma unroll
            for (int c = 0; c < 8; ++c) in[dx][c] = bf2f(raw[c]);
        }
        const float* wrow = dwT + (dy + 1) * 3 * Cc + c0;
        float wr[3][8];
#pragma unroll
        for (int tx = 0; tx < 3; ++tx) {
            float4 wa = *(const float4*)(wrow + tx * Cc);
            float4 wb = *(const float4*)(wrow + tx * Cc + 4);
            wr[tx][0] = wa.x; wr[tx][1] = wa.y; wr[tx][2] = wa.z; wr[tx][3] = wa.w;
            wr[tx][4] = wb.x; wr[tx][5] = wb.y; wr[tx][6] = wb.z; wr[tx][7] = wb.w;
        }
#pragma unroll
        for (int i = 0; i < 4; ++i)
#pragma unroll
            for (int tx = 0; tx < 3; ++tx)
#pragma unroll
                for (int c = 0; c < 8; ++c)
                    acc[i][c] += in[i + tx][c] * wr[tx][c];
    }

    const int s0 = c0 / CSZ - SPAD;
    const int s1 = (c0 + 4) / CSZ - SPAD;
#pragma unroll
    for (int i = 0; i < 4; ++i) {
        float g[8];
#pragma unroll
        for (int c = 0; c < 8; ++c) {
            const float v = acc[i][c];
            // gelu(v) ~= v * sigmoid(1.59576912*v + 0.07135482*v^3)
            const float u = v * v;
            const float a = __builtin_fmaf(0.0713548162f, u, 1.5957691216f);
            const float e = __expf(v * a);
            g[c] = v * e * __builtin_amdgcn_rcpf(e + 1.0f);
        }
        uint2 lo, hi;
        lo.x = pk2bf(g[0], g[1]); lo.y = pk2bf(g[2], g[3]);
        hi.x = pk2bf(g[4], g[5]); hi.y = pk2bf(g[6], g[7]);
        const int wo = wbase + 1 + i;
        const int w0 = wo + s0, w1 = wo + s1;
        if ((unsigned)w0 < (unsigned)Wc) *(uint2*)(gsh + (rowb + w0) * Cc + c0)     = lo;
        if ((unsigned)w1 < (unsigned)Wc) *(uint2*)(gsh + (rowb + w1) * Cc + c0 + 4) = hi;
    }
}

// ---------------------------------------------------------------------------
// K3: out = g_shifted @ w2b^T + b2. Clone of fc1's structure: BOTH panels
// bf16 via async16, single-barrier 1-step-lookahead, zero staging VALU.
// Epilogue writes fp32 out directly. LDS 32768 -> 5 blocks/CU by LDS.
// ---------------------------------------------------------------------------
__global__ __launch_bounds__(256)
void fc2_mfma_kernel(const unsigned short* __restrict__ A, const unsigned short* __restrict__ w2b,
                     const float* __restrict__ b2, float* __restrict__ out)
{
    __shared__ __align__(16) unsigned char smem[32768];
    __bf16* As = (__bf16*)smem;                  // [2][128][32]
    __bf16* Bs = (__bf16*)(smem + 16384);        // [2][128][32]

    const int tid  = threadIdx.x;
    const int lane = tid & 63;
    const int wave = tid >> 6;
    const int wm = (wave >> 1) * 64, wn = (wave & 1) * 64;

    const int lid = ((blockIdx.x & 7) << 8) | (blockIdx.x >> 3);
    const size_t m0 = (size_t)(lid >> 1) * 128;
    const int j0 = (lid & 1) * 128;
    const int idx0 = tid, idx1 = tid + 256;

    const size_t aro0 = (m0 + (idx0 >> 2)) * Cc + (idx0 & 3) * 8;
    const size_t aro1 = (m0 + (idx1 >> 2)) * Cc + (idx1 & 3) * 8;
    const size_t bro0 = (size_t)(j0 + (idx0 >> 2)) * Cc + (idx0 & 3) * 8;
    const size_t bro1 = (size_t)(j0 + (idx1 >> 2)) * Cc + (idx1 & 3) * 8;

    auto stage = [&](int buf, int t) {
        const int k0 = t * 32;
        __bf16* adst = As + buf * 4096;
        __bf16* bdst = Bs + buf * 4096;
        async16(A   + aro0 + k0, adst + idx0 * 8);
        async16(A   + aro1 + k0, adst + idx1 * 8);
        async16(w2b + bro0 + k0, bdst + idx0 * 8);
        async16(w2b + bro1 + k0, bdst + idx1 * 8);
    };

    f32x4 acc[4][4] = {};
    const int kq = (lane >> 4) * 8;
    const int rr = lane & 15;

    stage(0, 0);
    __syncthreads();

    int cur = 0;
    for (int t = 0; t < 8; ++t) {
        const int nxt = cur ^ 1;
        if (t < 7) stage(nxt, t + 1);
        bf16x8 a[4], b[4];
        const __bf16* ap = As + cur * 4096;
        const __bf16* bp = Bs + cur * 4096;
#pragma unroll
        for (int i = 0; i < 4; ++i) {
            a[i] = *(const bf16x8*)(ap + (wm + i * 16 + rr) * 32 + kq);
            b[i] = *(const bf16x8*)(bp + (wn + i * 16 + rr) * 32 + kq);
        }
#pragma unroll
        for (int i = 0; i < 4; ++i)
#pragma unroll
            for (int j = 0; j < 4; ++j)
                acc[i][j] = __builtin_amdgcn_mfma_f32_16x16x32_bf16(a[i], b[j], acc[i][j], 0, 0, 0);
        __syncthreads();
        cur = nxt;
    }

    const int cq = (lane >> 4) * 4;
    const int cc = lane & 15;
    float bv[4];
#pragma unroll
    for (int j = 0; j < 4; ++j) bv[j] = b2[j0 + wn + j * 16 + cc];
#pragma unroll
    for (int i = 0; i < 4; ++i)
#pragma unroll
        for (int j = 0; j < 4; ++j) {
            const int col = j0 + wn + j * 16 + cc;
#pragma unroll
            for (int rg = 0; rg < 4; ++rg)
                out[(m0 + wm + i * 16 + cq + rg) * Cc + col] = acc[i][j][rg] + bv[j];
        }
}

extern "C" void kernel_launch(void* const* d_in, const int* in_sizes, int n_in,
                              void* d_out, int out_size, void* d_ws, size_t ws_size,
                              hipStream_t stream) {
    // inputs: x, H, W, w1, b1, dw_w, dw_b, w2, b2
    const float* x    = (const float*)d_in[0];
    const float* w1   = (const float*)d_in[3];
    const float* b1   = (const float*)d_in[4];
    const float* dw_w = (const float*)d_in[5];
    const float* dw_b = (const float*)d_in[6];
    const float* w2   = (const float*)d_in[7];
    const float* b2   = (const float*)d_in[8];
    float* out = (float*)d_out;

    // ws layout (ws_size is 512 MiB; we use 128 MB + 265 KB):
    //   [0,64MB)    h1 bf16
    //   [64,128MB)  gsh bf16 (double-serves as x_bf16: fc1 consumes it
    //               before zero_borders/dwconv overwrite; stream-serial)
    //   [128MB..)   w1b bf16 (128 KB), w2b bf16 (128 KB), dwT fp32 (9 KB)
    unsigned short* h1  = (unsigned short*)d_ws;
    unsigned short* gsh = h1 + (size_t)Mtot * Cc;
    unsigned short* w1b = gsh + (size_t)Mtot * Cc;
    unsigned short* w2b = w1b + 65536;
    float*          dwT = (float*)(w2b + 65536);

    wprep_kernel<<<dim3(64), dim3(256), 0, stream>>>(w1, w2, dw_w, w1b, w2b, dwT);
    shiftcvt_kernel<<<dim3(4096), dim3(256), 0, stream>>>(x, gsh);
    fc1_mfma_kernel<<<dim3(2 * Mtot / 128), dim3(256), 0, stream>>>(gsh, w1b, b1, h1);
    zero_borders_kernel<<<dim3(512), dim3(256), 0, stream>>>(gsh);
    dwconv_gelu_scatter_kernel<<<dim3(4 * Mtot / 128), dim3(256), 0, stream>>>(h1, dwT, dw_b, gsh);
    fc2_mfma_kernel<<<dim3(2 * Mtot / 128), dim3(256), 0, stream>>>(gsh, w2b, b2, out);
}